// Round 10
// baseline (2856.068 us; speedup 1.0000x reference)
//
#include <hip/hip_runtime.h>
#include <math.h>

// ExperimentalModel_1752346656819: 4-stage dynamic-conv decoder, fp32 end-to-end.
// R9: convm rewritten as POLYPHASE conv — the 2x bilinear upsample is folded into
// precomputed 4x4 quarter-res weights (per fine-pixel parity). Kills the in-LDS
// expand phase + tile buffer (31KB->15KB LDS, 3 barriers->1, 6400->4096 FMAs).
// Exact border fallback (zero-padded fine taps) on image-edge tiles only.

#define BLK 256
#define EF 2.7182818284590452f

struct W1Args { const float* M[12]; float* out[12]; };
struct W2Args { const float* W[4]; const float* u[4]; const float* v[4]; float* out[4]; };

__device__ __forceinline__ float dln_one(float y, float m){
  float a = fabsf(y) - m;
  float v = __logf(__logf(a + EF) + 0.01f);
  return (y > 0.0f) ? v : -v;
}

__global__ void gather_ctx_kernel(const int* __restrict__ ids,
                                  const float* __restrict__ cache,
                                  float* __restrict__ ctx){
  int e = blockIdx.x*blockDim.x + threadIdx.x;
  if (e < 64*32){
    int b = e >> 5, l = e & 31;
    ctx[e] = cache[(size_t)ids[b]*32 + l];
  }
}

__global__ void gather_x_kernel(const int* __restrict__ ids,
                                const float* __restrict__ lat,
                                float* __restrict__ X, int b0, int nb){
  int total = nb*2048;
  int e = blockIdx.x*blockDim.x + threadIdx.x;
  if (e < total){
    int bl = e >> 11;
    int r  = e & 2047;
    X[e] = lat[(size_t)ids[b0+bl]*2048 + r];
  }
}

__global__ void w1_kernel(const float* __restrict__ ctx, W1Args args){
  const int S[12] = {4,4,4,4,4,4,4,4,4,1,1,1};
  const int K[12] = {128,1152,128,2048,128,3200,8,8,8,48,128,3};
  int tid = blockIdx.x*blockDim.x + threadIdx.x;
  int nth = gridDim.x*blockDim.x;
  for (int seg = 0; seg < 12; ++seg){
    const float* M = args.M[seg];
    float* out = args.out[seg];
    int Ks = K[seg];
    int total = S[seg]*64*Ks;
    for (int e = tid; e < total; e += nth){
      int k = e % Ks;
      int b = (e / Ks) % 64;
      int s = e / (Ks*64);
      const float* Ms = M + (size_t)s*32*Ks + k;
      const float* cb = ctx + b*32;
      float acc = 0.f;
      #pragma unroll
      for (int l = 0; l < 32; ++l) acc += cb[l]*Ms[(size_t)l*Ks];
      out[e] = acc;
    }
  }
}

// Dynamic weights. Segs 0-2 TRANSPOSED to [s][b][i][p][q][o]; seg 3 [b][o][i].
__global__ void w2_kernel(W2Args args){
  const int S[4] = {4,4,4,1};
  const int O[4] = {8,8,8,3};
  const int K[4] = {72,128,200,8};
  const int KH[4] = {3,4,5,1};
  int tid = blockIdx.x*blockDim.x + threadIdx.x;
  int nth = gridDim.x*blockDim.x;
  for (int seg = 0; seg < 4; ++seg){
    int Os = O[seg], Ks = K[seg];
    int kh = KH[seg], kk = kh*kh;
    int total = S[seg]*64*Os*Ks;
    const float* Wt = args.W[seg];
    const float* u = args.u[seg];
    const float* v = args.v[seg];
    float* out = args.out[seg];
    for (int e = tid; e < total; e += nth){
      int k = e % Ks;
      int o = (e/Ks) % Os;
      int b = (e/(Ks*Os)) % 64;
      int s = e/(Ks*Os*64);
      const float* us = u + (size_t)(s*64+b)*16*Os;
      const float* vs = v + (size_t)(s*64+b)*16*Ks;
      float mod = 0.f;
      #pragma unroll
      for (int r = 0; r < 16; ++r) mod += us[r*Os+o]*vs[r*Ks+k];
      float val = Wt[(size_t)(s*Os+o)*Ks + k] * (1.0f + mod + 1e-3f);
      size_t dst;
      if (seg < 3){
        int i = k / kk, r2 = k - i*kk, p = r2 / kh, q = r2 - p*kh;
        dst = (size_t)(s*64+b)*(8*Ks) + (size_t)(((i*kh+p)*kh+q)*8 + o);
      } else {
        dst = (size_t)b*24 + o*8 + k;
      }
      out[dst] = val;
    }
  }
}

// Build polyphase 5x5-on-upsampled weights: Wq[s][b][i][ey][ky][ex][kx][o]
// from wm [s][b][i][p][q][o].  Wq = sum_{p,q} wm * cy[ey][ky][p] * cy[ex][kx][q]
__global__ void w2m_kernel(const float* __restrict__ wm, float* __restrict__ wq){
  const float cy[2][4][5] = {
    {{0.25f,0,0,0,0},{0.75f,0.75f,0.25f,0,0},{0,0.25f,0.75f,0.75f,0.25f},{0,0,0,0.25f,0.75f}},
    {{0.75f,0.25f,0,0,0},{0.25f,0.75f,0.75f,0.25f,0},{0,0,0.25f,0.75f,0.75f},{0,0,0,0,0.25f}}};
  int total = 4*64*4096;
  for (int e = blockIdx.x*blockDim.x + threadIdx.x; e < total; e += gridDim.x*blockDim.x){
    int o  = e & 7;
    int kx = (e >> 3) & 3;
    int ex = (e >> 5) & 1;
    int ky = (e >> 6) & 3;
    int ey = (e >> 8) & 1;
    int i  = (e >> 9) & 7;
    int sb = e >> 12;                       // s*64+b
    const float* w5 = wm + (size_t)sb*1600;
    float acc = 0.f;
    #pragma unroll
    for (int p = 0; p < 5; ++p){
      float a = cy[ey][ky][p];
      if (a == 0.f) continue;
      #pragma unroll
      for (int q = 0; q < 5; ++q){
        float b = cy[ex][kx][q];
        if (b == 0.f) continue;
        acc += a*b*w5[((i*5+p)*5+q)*8 + o];
      }
    }
    wq[(size_t)sb*4096 + (size_t)(((i*2+ey)*4+ky)*64 + ex*32 + kx*8 + o)] = acc;
  }
}

__global__ void init_min_kernel(unsigned* __restrict__ mn, int n){
  int e = blockIdx.x*blockDim.x + threadIdx.x;
  if (e < n) mn[e] = 0x7F800000u;   // +inf
}

// 3x3 conv (pad 1). Block = 32x32 px tile, all 8 o. Two phases of 4 input ch.
__global__ void __launch_bounds__(BLK) convr_t8(
    const float* __restrict__ x, const float* __restrict__ wall,
    const float* __restrict__ ball, float* __restrict__ out,
    unsigned* __restrict__ mn, int H, int b0, int s, int tpr){
  __shared__ __align__(16) float tile[4*34*36];
  const int tiles = tpr*tpr;
  const int bl = blockIdx.x / tiles;
  const int t  = blockIdx.x - bl*tiles;
  const int Y0 = (t/tpr)*32, X0 = (t - (t/tpr)*tpr)*32;
  const int bg = b0 + bl;
  const float* wb = wall + (size_t)(s*64+bg)*576;
  const float* bb = ball + (s*64+bg)*8;
  const int HW = H*H;
  const float* xb = x + (size_t)bl*8*HW;
  const int tx = threadIdx.x & 7, ty = threadIdx.x >> 3;
  const bool act = (Y0+ty < H) && (X0+4*tx < H);  // only false when H==16
  float a[8][4];
  #pragma unroll
  for (int o = 0; o < 8; ++o){
    float b = bb[o];
    a[o][0]=b; a[o][1]=b; a[o][2]=b; a[o][3]=b;
  }
  #pragma unroll 1
  for (int ph = 0; ph < 2; ++ph){
    __syncthreads();
    {
      float vb[10];
      #pragma unroll
      for (int k = 0; k < 10; ++k){
        int e = threadIdx.x + k*BLK;
        int cc = e % 36; int rr = (e/36) % 34; int c4 = e/(36*34);
        int gy = Y0 - 1 + rr, gx = X0 - 1 + cc;
        float v = 0.f;
        if (cc < 34 && (unsigned)gy < (unsigned)H && (unsigned)gx < (unsigned)H)
          v = xb[(size_t)(ph*4 + c4)*HW + gy*H + gx];
        vb[k] = v;
      }
      #pragma unroll
      for (int k = 0; k < 10; ++k) tile[threadIdx.x + k*BLK] = vb[k];
    }
    {
      float vb[10];
      #pragma unroll
      for (int k = 0; k < 10; ++k){
        int e = threadIdx.x + (k+10)*BLK;
        float v = 0.f;
        if (e < 4896){
          int cc = e % 36; int rr = (e/36) % 34; int c4 = e/(36*34);
          int gy = Y0 - 1 + rr, gx = X0 - 1 + cc;
          if (cc < 34 && (unsigned)gy < (unsigned)H && (unsigned)gx < (unsigned)H)
            v = xb[(size_t)(ph*4 + c4)*HW + gy*H + gx];
        }
        vb[k] = v;
      }
      #pragma unroll
      for (int k = 0; k < 10; ++k){
        int e = threadIdx.x + (k+10)*BLK;
        if (e < 4896) tile[e] = vb[k];
      }
    }
    __syncthreads();
    #pragma unroll 1
    for (int i = 0; i < 4; ++i){
      const float* tch = tile + i*1224;
      const int ig = ph*4 + i;
      #pragma unroll
      for (int p = 0; p < 3; ++p){
        const float* row = tch + (ty+p)*36 + 4*tx;
        float4 c0 = *(const float4*)row;
        float4 c1 = *(const float4*)(row+4);
        float c[8] = {c0.x,c0.y,c0.z,c0.w,c1.x,c1.y,c1.z,c1.w};
        const float* wip = wb + (ig*3+p)*24;
        float w[24];
        #pragma unroll
        for (int k = 0; k < 24; ++k) w[k] = wip[k];
        #pragma unroll
        for (int q = 0; q < 3; ++q){
          #pragma unroll
          for (int o = 0; o < 8; ++o){
            float wq = w[q*8+o];
            a[o][0] += wq*c[q];   a[o][1] += wq*c[q+1];
            a[o][2] += wq*c[q+2]; a[o][3] += wq*c[q+3];
          }
        }
      }
    }
  }
  float lm[8];
  #pragma unroll
  for (int o = 0; o < 8; ++o){
    float v = act ? fminf(fminf(fabsf(a[o][0]),fabsf(a[o][1])),
                          fminf(fabsf(a[o][2]),fabsf(a[o][3]))) : 3.4e38f;
    #pragma unroll
    for (int off = 32; off > 0; off >>= 1) v = fminf(v, __shfl_xor(v, off));
    lm[o] = v;
    if (act){
      *(float4*)(out + ((size_t)(bl*8+o))*HW + (Y0+ty)*H + X0 + 4*tx) =
          make_float4(a[o][0],a[o][1],a[o][2],a[o][3]);
    }
  }
  if ((threadIdx.x & 63) == 0){
    #pragma unroll
    for (int o = 0; o < 8; ++o) atomicMin(mn + bl*8 + o, __float_as_uint(lm[o]));
  }
}

// 4x4 stride-2 transposed conv of (-x) (pad 1). Block = 32x32 OUTPUT tile, all 8 o.
__global__ void __launch_bounds__(BLK) convt_t8(
    const float* __restrict__ x, const float* __restrict__ wall,
    const float* __restrict__ ball, float* __restrict__ out,
    unsigned* __restrict__ mn, int H, int b0, int s, int tpr){
  __shared__ float tile[8*18*20];
  const int tiles = tpr*tpr;
  const int bl = blockIdx.x / tiles;
  const int t  = blockIdx.x - bl*tiles;
  const int Y0 = (t/tpr)*32, X0 = (t - (t/tpr)*tpr)*32;  // output coords
  const int bg = b0 + bl;
  const float* wb = wall + (size_t)(s*64+bg)*1024;
  const float* bb = ball + (s*64+bg)*8;
  const int Ho = 2*H, HWo = Ho*Ho, HW = H*H;
  const float* xb = x + (size_t)bl*8*HW;
  const int ry0 = Y0/2 - 1, rx0 = X0/2 - 1;
  {
    float vb[12];
    #pragma unroll
    for (int k = 0; k < 12; ++k){
      int e = threadIdx.x + k*BLK;
      float v = 0.f;
      if (e < 2880){
        int cc = e % 20; int rr = (e/20) % 18; int ch = e/(20*18);
        int gy = ry0 + rr, gx = rx0 + cc;
        if (cc < 18 && (unsigned)gy < (unsigned)H && (unsigned)gx < (unsigned)H)
          v = xb[(size_t)ch*HW + gy*H + gx];
      }
      vb[k] = v;
    }
    #pragma unroll
    for (int k = 0; k < 12; ++k){
      int e = threadIdx.x + k*BLK;
      if (e < 2880) tile[e] = vb[k];
    }
  }
  __syncthreads();
  const int tx = threadIdx.x & 7;
  const int ty2 = threadIdx.x >> 3;
  const int row = (ty2 < 16) ? 2*ty2 : 2*(ty2-16)+1;   // wave-parity-uniform
  const int yodd = __builtin_amdgcn_readfirstlane(row & 1);
  const int half = row >> 1;
  const int pA = yodd ? 0 : 1, rA = yodd ? half+2 : half+1;
  const int pB = yodd ? 2 : 3, rB = yodd ? half+1 : half;
  float a[8][4];
  #pragma unroll
  for (int o = 0; o < 8; ++o){
    float b = bb[o];
    a[o][0]=b; a[o][1]=b; a[o][2]=b; a[o][3]=b;
  }
  #pragma unroll 1
  for (int i = 0; i < 8; ++i){
    #pragma unroll
    for (int rt = 0; rt < 2; ++rt){
      const int p = rt ? pB : pA;
      const int ri = rt ? rB : rA;
      const float* rowp = tile + i*360 + ri*20 + 2*tx;
      float e0 = rowp[0], e1 = rowp[1], e2 = rowp[2], e3 = rowp[3];
      const float* wip = wb + (i*4+p)*32;   // [q][o], uniform
      float w[32];
      #pragma unroll
      for (int k = 0; k < 32; ++k) w[k] = wip[k];
      #pragma unroll
      for (int o = 0; o < 8; ++o){
        float w1 = w[8+o];  a[o][0] -= w1*e1; a[o][2] -= w1*e2;  // x even, q=1
        float w3 = w[24+o]; a[o][0] -= w3*e0; a[o][2] -= w3*e1;  // x even, q=3
        float w0 = w[o];    a[o][1] -= w0*e2; a[o][3] -= w0*e3;  // x odd,  q=0
        float w2 = w[16+o]; a[o][1] -= w2*e1; a[o][3] -= w2*e2;  // x odd,  q=2
      }
    }
  }
  float lm[8];
  #pragma unroll
  for (int o = 0; o < 8; ++o){
    float v = fminf(fminf(fabsf(a[o][0]),fabsf(a[o][1])),
                    fminf(fabsf(a[o][2]),fabsf(a[o][3])));
    #pragma unroll
    for (int off = 32; off > 0; off >>= 1) v = fminf(v, __shfl_xor(v, off));
    lm[o] = v;
    *(float4*)(out + ((size_t)(bl*8+o))*HWo + (Y0+row)*Ho + X0 + 4*tx) =
        make_float4(a[o][0],a[o][1],a[o][2],a[o][3]);
  }
  if ((threadIdx.x & 63) == 0){
    #pragma unroll
    for (int o = 0; o < 8; ++o) atomicMin(mn + bl*8 + o, __float_as_uint(lm[o]));
  }
}

// POLYPHASE 5x5-on-upsampled conv. Quarter-res log halo in LDS (clamp-extended),
// 4x4 quarter-taps per fine-parity; exact zero-pad fallback on image-edge px.
__global__ void __launch_bounds__(BLK) convm_poly(
    const float* __restrict__ X, const float* __restrict__ wqall,
    const float* __restrict__ wall, const float* __restrict__ ball,
    float* __restrict__ out, unsigned* __restrict__ mn,
    int Hi, int b0, int s, int tpr){
  __shared__ __align__(16) float lbuf[8*20*24];     // 15.4 KB, stride 24
  const int tiles = tpr*tpr;
  const int bl = blockIdx.x / tiles;
  const int t  = blockIdx.x - bl*tiles;
  const int Y0 = (t/tpr)*32, X0 = (t - (t/tpr)*tpr)*32;
  const int bg = b0 + bl;
  const float* wq = wqall + (size_t)(s*64+bg)*4096;
  const float* w5 = wall + (size_t)(s*64+bg)*1600;  // original [i][p][q][o]
  const float* bb = ball + (s*64+bg)*8;
  const int Hq = Hi >> 1, HWq = Hq*Hq;
  const int HW = Hi*Hi;
  const float* xb = X + (size_t)bl*8*HWq;
  const int LY0 = (Y0 >> 1) - 2;
  const int LX0 = (X0 >> 1) - 2;
  // stage: 8 ch x 20 x 20 (stride 24), clamp-extended, log applied
  for (int e = threadIdx.x; e < 3200; e += BLK){
    int cc = e % 20; int rr = (e/20) % 20; int ch = e/400;
    int ly = LY0 + rr; ly = (ly < 0) ? 0 : ((ly >= Hq) ? Hq-1 : ly);
    int lx = LX0 + cc; lx = (lx < 0) ? 0 : ((lx >= Hq) ? Hq-1 : lx);
    lbuf[ch*480 + rr*24 + cc] = __logf(fabsf(xb[(size_t)ch*HWq + ly*Hq + lx]) + 1.0f);
  }
  __syncthreads();
  const int tx = threadIdx.x & 7;
  const int ty2 = threadIdx.x >> 3;
  const int row = (ty2 < 16) ? 2*ty2 : 2*(ty2-16)+1;   // wave-parity-uniform
  const int ey = __builtin_amdgcn_readfirstlane(row & 1);
  const int y = Y0 + row;
  const int rbase = (row >> 1) + ey;                   // rel row of ky=0 tap
  float a[8][4];
  #pragma unroll
  for (int o = 0; o < 8; ++o){
    float b = bb[o];
    a[o][0]=b; a[o][1]=b; a[o][2]=b; a[o][3]=b;
  }
  #pragma unroll 1
  for (int i = 0; i < 8; ++i){
    const float* lch = lbuf + i*480;
    #pragma unroll
    for (int ky = 0; ky < 4; ++ky){
      const float* lr = lch + (rbase + ky)*24 + 2*tx;
      float2 f0 = *(const float2*)lr;
      float2 f1 = *(const float2*)(lr+2);
      float2 f2 = *(const float2*)(lr+4);
      float l[6] = {f0.x,f0.y,f1.x,f1.y,f2.x,f2.y};
      const float* wk = wq + (((i*2+ey)*4 + ky) << 6);  // [ex][kx][o], uniform
      float w[64];
      #pragma unroll
      for (int k = 0; k < 64; ++k) w[k] = wk[k];
      #pragma unroll
      for (int kx = 0; kx < 4; ++kx){
        #pragma unroll
        for (int o = 0; o < 8; ++o){
          float w0 = w[kx*8+o];        // ex=0
          float w1 = w[32+kx*8+o];     // ex=1
          a[o][0] += w0*l[kx];   a[o][2] += w0*l[kx+1];
          a[o][1] += w1*l[kx+1]; a[o][3] += w1*l[kx+2];
        }
      }
    }
  }
  // exact fallback for fine px whose 5x5 taps exit the image (zero-padded there)
  if (Y0 == 0 || Y0 == Hi-32 || X0 == 0 || X0 == Hi-32){
    const bool ybad = (y < 2) || (y >= Hi-2);
    #pragma unroll 1
    for (int j = 0; j < 4; ++j){
      int x = X0 + 4*tx + j;
      if (!(ybad || x < 2 || x >= Hi-2)) continue;
      float acc2[8];
      #pragma unroll
      for (int o = 0; o < 8; ++o) acc2[o] = bb[o];
      #pragma unroll 1
      for (int i = 0; i < 8; ++i){
        const float* lch = lbuf + i*480;
        #pragma unroll 1
        for (int p = 0; p < 5; ++p){
          int tf = y + p - 2;
          if ((unsigned)tf >= (unsigned)Hi) continue;
          int jt = tf >> 1;
          int nt = (tf & 1) ? jt+1 : jt-1;
          nt = (nt < 0) ? 0 : ((nt >= Hq) ? Hq-1 : nt);
          int rj = jt - LY0, rn = nt - LY0;
          #pragma unroll 1
          for (int q = 0; q < 5; ++q){
            int uf = x + q - 2;
            if ((unsigned)uf >= (unsigned)Hi) continue;
            int ju = uf >> 1;
            int nu = (uf & 1) ? ju+1 : ju-1;
            nu = (nu < 0) ? 0 : ((nu >= Hq) ? Hq-1 : nu);
            int cj = ju - LX0, cn = nu - LX0;
            float U = 0.5625f*lch[rj*24+cj] + 0.1875f*(lch[rj*24+cn] + lch[rn*24+cj])
                    + 0.0625f*lch[rn*24+cn];
            const float* wv = w5 + ((i*5+p)*5+q)*8;
            #pragma unroll
            for (int o = 0; o < 8; ++o) acc2[o] += wv[o]*U;
          }
        }
      }
      #pragma unroll
      for (int o = 0; o < 8; ++o) a[o][j] = acc2[o];
    }
  }
  float lm[8];
  #pragma unroll
  for (int o = 0; o < 8; ++o){
    float v = fminf(fminf(fabsf(a[o][0]),fabsf(a[o][1])),
                    fminf(fabsf(a[o][2]),fabsf(a[o][3])));
    #pragma unroll
    for (int off = 32; off > 0; off >>= 1) v = fminf(v, __shfl_xor(v, off));
    lm[o] = v;
    *(float4*)(out + ((size_t)(bl*8+o))*HW + (Y0+row)*Hi + X0 + 4*tx) =
        make_float4(a[o][0],a[o][1],a[o][2],a[o][3]);
  }
  if ((threadIdx.x & 63) == 0){
    #pragma unroll
    for (int o = 0; o < 8; ++o) atomicMin(mn + bl*8 + o, __float_as_uint(lm[o]));
  }
}

// s<3: next_x = (dln(Dr)[nearest-up] + dln(Dt)) * dln(Dm), into X. Quarter-px threads.
__global__ void combine_kernel(const float* __restrict__ dr, const float* __restrict__ dt,
                               const float* __restrict__ dm,
                               const unsigned* __restrict__ mn, int maps,
                               float* __restrict__ outx, int H, int total){
  int Ho = 2*H, HWo = Ho*Ho, HW = H*H;
  for (int e = blockIdx.x*blockDim.x + threadIdx.x; e < total; e += gridDim.x*blockDim.x){
    int m = e / HW;
    int qpx = e - m*HW;
    int qy = qpx / H, qx = qpx - qy*H;
    float mr = __uint_as_float(mn[m]);
    float mt = __uint_as_float(mn[maps + m]);
    float mm = __uint_as_float(mn[2*maps + m]);
    float r = dln_one(dr[(size_t)m*HW + qpx], mr);
    #pragma unroll
    for (int dy = 0; dy < 2; ++dy){
      size_t base = (size_t)m*HWo + (2*qy+dy)*Ho + 2*qx;
      float2 tv = *(const float2*)(dt + base);
      float2 mv = *(const float2*)(dm + base);
      float2 ov;
      ov.x = (r + dln_one(tv.x, mt)) * dln_one(mv.x, mm);
      ov.y = (r + dln_one(tv.y, mt)) * dln_one(mv.y, mm);
      *(float2*)(outx + base) = ov;
    }
  }
}

// s==3: combine + final dynamic 1x1 conv (8->3 ch) fused, writes d_out.
__global__ void combineF_kernel(const float* __restrict__ dr, const float* __restrict__ dt,
                                const float* __restrict__ dm,
                                const unsigned* __restrict__ mn, int maps,
                                const float* __restrict__ wo, const float* __restrict__ bo,
                                float* __restrict__ out, int b0, int total){
  for (int e = blockIdx.x*blockDim.x + threadIdx.x; e < total; e += gridDim.x*blockDim.x){
    int bl = e >> 14;
    int qpx = e & 16383;
    int qy = qpx >> 7, qx = qpx & 127;
    int bg = b0 + bl;
    float r[8], mtv[8], mmv[8];
    #pragma unroll
    for (int o = 0; o < 8; ++o){
      int m = bl*8 + o;
      float mr = __uint_as_float(mn[m]);
      mtv[o] = __uint_as_float(mn[maps + m]);
      mmv[o] = __uint_as_float(mn[2*maps + m]);
      r[o] = dln_one(dr[(size_t)m*16384 + qpx], mr);
    }
    #pragma unroll
    for (int dy = 0; dy < 2; ++dy){
      int y = 2*qy + dy, xx = 2*qx;
      float2 acc[3];
      #pragma unroll
      for (int of = 0; of < 3; ++of){
        float b = bo[bg*3 + of];
        acc[of].x = b; acc[of].y = b;
      }
      #pragma unroll
      for (int o = 0; o < 8; ++o){
        size_t base = (size_t)(bl*8+o)*65536 + y*256 + xx;
        float2 tv = *(const float2*)(dt + base);
        float2 mv = *(const float2*)(dm + base);
        float vx = (r[o] + dln_one(tv.x, mtv[o])) * dln_one(mv.x, mmv[o]);
        float vy = (r[o] + dln_one(tv.y, mtv[o])) * dln_one(mv.y, mmv[o]);
        #pragma unroll
        for (int of = 0; of < 3; ++of){
          float w = wo[bg*24 + of*8 + o];
          acc[of].x += w*vx; acc[of].y += w*vy;
        }
      }
      #pragma unroll
      for (int of = 0; of < 3; ++of){
        *(float2*)(out + ((size_t)(bg*3 + of))*65536 + y*256 + xx) = acc[of];
      }
    }
  }
}

static inline int grid_for(long long total){
  long long g = (total + BLK - 1) / BLK;
  if (g > 16384) g = 16384;
  if (g < 1) g = 1;
  return (int)g;
}

extern "C" void kernel_launch(void* const* d_in, const int* in_sizes, int n_in,
                              void* d_out, int out_size, void* d_ws, size_t ws_size,
                              hipStream_t stream){
  (void)in_sizes; (void)n_in; (void)out_size;
  const int*   ids   = (const int*)d_in[0];
  const float* cache = (const float*)d_in[1];
  const float* lat   = (const float*)d_in[2];
  const float* Wr = (const float*)d_in[3];
  const float* Ur = (const float*)d_in[4];
  const float* Vr = (const float*)d_in[5];
  const float* Br = (const float*)d_in[6];
  const float* Wt = (const float*)d_in[7];
  const float* Ut = (const float*)d_in[8];
  const float* Vt = (const float*)d_in[9];
  const float* Bt = (const float*)d_in[10];
  const float* Wm = (const float*)d_in[11];
  const float* Um = (const float*)d_in[12];
  const float* Vm = (const float*)d_in[13];
  const float* Bm = (const float*)d_in[14];
  const float* Wo = (const float*)d_in[15];
  const float* Uo = (const float*)d_in[16];
  const float* Vo = (const float*)d_in[17];
  const float* Bo = (const float*)d_in[18];
  float* out = (float*)d_out;
  float* ws  = (float*)d_ws;

  size_t off = 0;
  auto alloc = [&](size_t n){ size_t o = off; off += n; return o; };
  size_t o_ctx = alloc(2048);
  size_t o_ur = alloc(4*64*128),  o_vr = alloc(4*64*1152);
  size_t o_ut = alloc(4*64*128),  o_vt = alloc(4*64*2048);
  size_t o_um = alloc(4*64*128),  o_vm = alloc(4*64*3200);
  size_t o_br = alloc(4*64*8), o_bt = alloc(4*64*8), o_bm = alloc(4*64*8);
  size_t o_uo = alloc(64*48), o_vo = alloc(64*128), o_bo = alloc(64*3);
  size_t o_wr = alloc(4*64*8*72), o_wt = alloc(4*64*8*128), o_wm = alloc(4*64*8*200);
  size_t o_wo = alloc(64*24);
  size_t o_wmq = alloc(4*64*4096);       // polyphase convm weights
  size_t o_mn = alloc(4*3*512);          // [stage][3][maps]
  size_t small_end = off;

  // per sample: X (8*128^2) + D (8*128^2) + T (8*256^2) + M (8*256^2)
  const size_t perS = 2*(size_t)131072 + 2*(size_t)524288;
  size_t ws_f = ws_size / sizeof(float);
  int nb = 64;
  while (nb > 1 && small_end + (size_t)nb*perS > ws_f) nb >>= 1;

  size_t o_X = small_end;
  size_t o_D = o_X + (size_t)nb*131072;
  size_t o_T = o_D + (size_t)nb*131072;
  size_t o_M = o_T + (size_t)nb*524288;
  unsigned* mn = (unsigned*)(ws + o_mn);

  gather_ctx_kernel<<<8, BLK, 0, stream>>>(ids, cache, ws + o_ctx);

  W1Args a1;
  a1.M[0]=Ur;  a1.out[0]=ws+o_ur;
  a1.M[1]=Vr;  a1.out[1]=ws+o_vr;
  a1.M[2]=Ut;  a1.out[2]=ws+o_ut;
  a1.M[3]=Vt;  a1.out[3]=ws+o_vt;
  a1.M[4]=Um;  a1.out[4]=ws+o_um;
  a1.M[5]=Vm;  a1.out[5]=ws+o_vm;
  a1.M[6]=Br;  a1.out[6]=ws+o_br;
  a1.M[7]=Bt;  a1.out[7]=ws+o_bt;
  a1.M[8]=Bm;  a1.out[8]=ws+o_bm;
  a1.M[9]=Uo;  a1.out[9]=ws+o_uo;
  a1.M[10]=Vo; a1.out[10]=ws+o_vo;
  a1.M[11]=Bo; a1.out[11]=ws+o_bo;
  w1_kernel<<<256, BLK, 0, stream>>>(ws + o_ctx, a1);

  W2Args a2;
  a2.W[0]=Wr; a2.u[0]=ws+o_ur; a2.v[0]=ws+o_vr; a2.out[0]=ws+o_wr;
  a2.W[1]=Wt; a2.u[1]=ws+o_ut; a2.v[1]=ws+o_vt; a2.out[1]=ws+o_wt;
  a2.W[2]=Wm; a2.u[2]=ws+o_um; a2.v[2]=ws+o_vm; a2.out[2]=ws+o_wm;
  a2.W[3]=Wo; a2.u[3]=ws+o_uo; a2.v[3]=ws+o_vo; a2.out[3]=ws+o_wo;
  w2_kernel<<<256, BLK, 0, stream>>>(a2);
  w2m_kernel<<<512, BLK, 0, stream>>>(ws+o_wm, ws+o_wmq);

  for (int b0 = 0; b0 < 64; b0 += nb){
    gather_x_kernel<<<grid_for((long long)nb*2048), BLK, 0, stream>>>(
        ids, lat, ws+o_X, b0, nb);
    int maps = nb*8;
    init_min_kernel<<<(4*3*maps + BLK-1)/BLK, BLK, 0, stream>>>(mn, 4*3*maps);
    int H = 16;
    for (int s = 0; s < 4; ++s){
      int Ho = 2*H;
      int tprR = (H >= 32) ? H/32 : 1;
      int tprO = Ho/32;
      unsigned* mns = mn + (size_t)s*3*maps;
      convr_t8<<<nb*tprR*tprR, BLK, 0, stream>>>(ws+o_X, ws+o_wr, ws+o_br, ws+o_D, mns,            H,  b0, s, tprR);
      convt_t8<<<nb*tprO*tprO, BLK, 0, stream>>>(ws+o_X, ws+o_wt, ws+o_bt, ws+o_T, mns + maps,     H,  b0, s, tprO);
      convm_poly<<<nb*tprO*tprO, BLK, 0, stream>>>(ws+o_X, ws+o_wmq, ws+o_wm, ws+o_bm, ws+o_M,
                                                   mns + 2*maps, Ho, b0, s, tprO);
      if (s < 3){
        long long totalq = (long long)maps*H*H;
        combine_kernel<<<grid_for(totalq), BLK, 0, stream>>>(
            ws+o_D, ws+o_T, ws+o_M, mns, maps, ws+o_X, H, (int)totalq);
      } else {
        long long totalf = (long long)nb*16384;
        combineF_kernel<<<grid_for(totalf), BLK, 0, stream>>>(
            ws+o_D, ws+o_T, ws+o_M, mns, maps, ws+o_wo, ws+o_bo, out, b0, (int)totalf);
      }
      H = Ho;
    }
  }
}

// Round 11
// 2737.830 us; speedup vs baseline: 1.0432x; 1.0432x over previous
//
#include <hip/hip_runtime.h>
#include <math.h>

// ExperimentalModel_1752346656819: 4-stage dynamic-conv decoder, fp32 end-to-end.
// R10: R9 polyphase convm with the register-demotion bug fixed — the border
// fallback's j-loop is now fully unrolled so a[o][j] is static indexing
// (R9's runtime j demoted the whole accumulator array to scratch: VGPR=36,
// every FMA round-tripped scratch memory).

#define BLK 256
#define EF 2.7182818284590452f

struct W1Args { const float* M[12]; float* out[12]; };
struct W2Args { const float* W[4]; const float* u[4]; const float* v[4]; float* out[4]; };

__device__ __forceinline__ float dln_one(float y, float m){
  float a = fabsf(y) - m;
  float v = __logf(__logf(a + EF) + 0.01f);
  return (y > 0.0f) ? v : -v;
}

__global__ void gather_ctx_kernel(const int* __restrict__ ids,
                                  const float* __restrict__ cache,
                                  float* __restrict__ ctx){
  int e = blockIdx.x*blockDim.x + threadIdx.x;
  if (e < 64*32){
    int b = e >> 5, l = e & 31;
    ctx[e] = cache[(size_t)ids[b]*32 + l];
  }
}

__global__ void gather_x_kernel(const int* __restrict__ ids,
                                const float* __restrict__ lat,
                                float* __restrict__ X, int b0, int nb){
  int total = nb*2048;
  int e = blockIdx.x*blockDim.x + threadIdx.x;
  if (e < total){
    int bl = e >> 11;
    int r  = e & 2047;
    X[e] = lat[(size_t)ids[b0+bl]*2048 + r];
  }
}

__global__ void w1_kernel(const float* __restrict__ ctx, W1Args args){
  const int S[12] = {4,4,4,4,4,4,4,4,4,1,1,1};
  const int K[12] = {128,1152,128,2048,128,3200,8,8,8,48,128,3};
  int tid = blockIdx.x*blockDim.x + threadIdx.x;
  int nth = gridDim.x*blockDim.x;
  for (int seg = 0; seg < 12; ++seg){
    const float* M = args.M[seg];
    float* out = args.out[seg];
    int Ks = K[seg];
    int total = S[seg]*64*Ks;
    for (int e = tid; e < total; e += nth){
      int k = e % Ks;
      int b = (e / Ks) % 64;
      int s = e / (Ks*64);
      const float* Ms = M + (size_t)s*32*Ks + k;
      const float* cb = ctx + b*32;
      float acc = 0.f;
      #pragma unroll
      for (int l = 0; l < 32; ++l) acc += cb[l]*Ms[(size_t)l*Ks];
      out[e] = acc;
    }
  }
}

// Dynamic weights. Segs 0-2 TRANSPOSED to [s][b][i][p][q][o]; seg 3 [b][o][i].
__global__ void w2_kernel(W2Args args){
  const int S[4] = {4,4,4,1};
  const int O[4] = {8,8,8,3};
  const int K[4] = {72,128,200,8};
  const int KH[4] = {3,4,5,1};
  int tid = blockIdx.x*blockDim.x + threadIdx.x;
  int nth = gridDim.x*blockDim.x;
  for (int seg = 0; seg < 4; ++seg){
    int Os = O[seg], Ks = K[seg];
    int kh = KH[seg], kk = kh*kh;
    int total = S[seg]*64*Os*Ks;
    const float* Wt = args.W[seg];
    const float* u = args.u[seg];
    const float* v = args.v[seg];
    float* out = args.out[seg];
    for (int e = tid; e < total; e += nth){
      int k = e % Ks;
      int o = (e/Ks) % Os;
      int b = (e/(Ks*Os)) % 64;
      int s = e/(Ks*Os*64);
      const float* us = u + (size_t)(s*64+b)*16*Os;
      const float* vs = v + (size_t)(s*64+b)*16*Ks;
      float mod = 0.f;
      #pragma unroll
      for (int r = 0; r < 16; ++r) mod += us[r*Os+o]*vs[r*Ks+k];
      float val = Wt[(size_t)(s*Os+o)*Ks + k] * (1.0f + mod + 1e-3f);
      size_t dst;
      if (seg < 3){
        int i = k / kk, r2 = k - i*kk, p = r2 / kh, q = r2 - p*kh;
        dst = (size_t)(s*64+b)*(8*Ks) + (size_t)(((i*kh+p)*kh+q)*8 + o);
      } else {
        dst = (size_t)b*24 + o*8 + k;
      }
      out[dst] = val;
    }
  }
}

// Build polyphase 5x5-on-upsampled weights: Wq[s][b][i][ey][ky][ex][kx][o]
__global__ void w2m_kernel(const float* __restrict__ wm, float* __restrict__ wq){
  const float cy[2][4][5] = {
    {{0.25f,0,0,0,0},{0.75f,0.75f,0.25f,0,0},{0,0.25f,0.75f,0.75f,0.25f},{0,0,0,0.25f,0.75f}},
    {{0.75f,0.25f,0,0,0},{0.25f,0.75f,0.75f,0.25f,0},{0,0,0.25f,0.75f,0.75f},{0,0,0,0,0.25f}}};
  int total = 4*64*4096;
  for (int e = blockIdx.x*blockDim.x + threadIdx.x; e < total; e += gridDim.x*blockDim.x){
    int o  = e & 7;
    int kx = (e >> 3) & 3;
    int ex = (e >> 5) & 1;
    int ky = (e >> 6) & 3;
    int ey = (e >> 8) & 1;
    int i  = (e >> 9) & 7;
    int sb = e >> 12;                       // s*64+b
    const float* w5 = wm + (size_t)sb*1600;
    float acc = 0.f;
    #pragma unroll
    for (int p = 0; p < 5; ++p){
      float a = cy[ey][ky][p];
      if (a == 0.f) continue;
      #pragma unroll
      for (int q = 0; q < 5; ++q){
        float b = cy[ex][kx][q];
        if (b == 0.f) continue;
        acc += a*b*w5[((i*5+p)*5+q)*8 + o];
      }
    }
    wq[(size_t)sb*4096 + (size_t)(((i*2+ey)*4+ky)*64 + ex*32 + kx*8 + o)] = acc;
  }
}

__global__ void init_min_kernel(unsigned* __restrict__ mn, int n){
  int e = blockIdx.x*blockDim.x + threadIdx.x;
  if (e < n) mn[e] = 0x7F800000u;   // +inf
}

// 3x3 conv (pad 1). Block = 32x32 px tile, all 8 o. Two phases of 4 input ch.
__global__ void __launch_bounds__(BLK) convr_t8(
    const float* __restrict__ x, const float* __restrict__ wall,
    const float* __restrict__ ball, float* __restrict__ out,
    unsigned* __restrict__ mn, int H, int b0, int s, int tpr){
  __shared__ __align__(16) float tile[4*34*36];
  const int tiles = tpr*tpr;
  const int bl = blockIdx.x / tiles;
  const int t  = blockIdx.x - bl*tiles;
  const int Y0 = (t/tpr)*32, X0 = (t - (t/tpr)*tpr)*32;
  const int bg = b0 + bl;
  const float* wb = wall + (size_t)(s*64+bg)*576;
  const float* bb = ball + (s*64+bg)*8;
  const int HW = H*H;
  const float* xb = x + (size_t)bl*8*HW;
  const int tx = threadIdx.x & 7, ty = threadIdx.x >> 3;
  const bool act = (Y0+ty < H) && (X0+4*tx < H);  // only false when H==16
  float a[8][4];
  #pragma unroll
  for (int o = 0; o < 8; ++o){
    float b = bb[o];
    a[o][0]=b; a[o][1]=b; a[o][2]=b; a[o][3]=b;
  }
  #pragma unroll 1
  for (int ph = 0; ph < 2; ++ph){
    __syncthreads();
    {
      float vb[10];
      #pragma unroll
      for (int k = 0; k < 10; ++k){
        int e = threadIdx.x + k*BLK;
        int cc = e % 36; int rr = (e/36) % 34; int c4 = e/(36*34);
        int gy = Y0 - 1 + rr, gx = X0 - 1 + cc;
        float v = 0.f;
        if (cc < 34 && (unsigned)gy < (unsigned)H && (unsigned)gx < (unsigned)H)
          v = xb[(size_t)(ph*4 + c4)*HW + gy*H + gx];
        vb[k] = v;
      }
      #pragma unroll
      for (int k = 0; k < 10; ++k) tile[threadIdx.x + k*BLK] = vb[k];
    }
    {
      float vb[10];
      #pragma unroll
      for (int k = 0; k < 10; ++k){
        int e = threadIdx.x + (k+10)*BLK;
        float v = 0.f;
        if (e < 4896){
          int cc = e % 36; int rr = (e/36) % 34; int c4 = e/(36*34);
          int gy = Y0 - 1 + rr, gx = X0 - 1 + cc;
          if (cc < 34 && (unsigned)gy < (unsigned)H && (unsigned)gx < (unsigned)H)
            v = xb[(size_t)(ph*4 + c4)*HW + gy*H + gx];
        }
        vb[k] = v;
      }
      #pragma unroll
      for (int k = 0; k < 10; ++k){
        int e = threadIdx.x + (k+10)*BLK;
        if (e < 4896) tile[e] = vb[k];
      }
    }
    __syncthreads();
    #pragma unroll 1
    for (int i = 0; i < 4; ++i){
      const float* tch = tile + i*1224;
      const int ig = ph*4 + i;
      #pragma unroll
      for (int p = 0; p < 3; ++p){
        const float* row = tch + (ty+p)*36 + 4*tx;
        float4 c0 = *(const float4*)row;
        float4 c1 = *(const float4*)(row+4);
        float c[8] = {c0.x,c0.y,c0.z,c0.w,c1.x,c1.y,c1.z,c1.w};
        const float* wip = wb + (ig*3+p)*24;
        float w[24];
        #pragma unroll
        for (int k = 0; k < 24; ++k) w[k] = wip[k];
        #pragma unroll
        for (int q = 0; q < 3; ++q){
          #pragma unroll
          for (int o = 0; o < 8; ++o){
            float wq = w[q*8+o];
            a[o][0] += wq*c[q];   a[o][1] += wq*c[q+1];
            a[o][2] += wq*c[q+2]; a[o][3] += wq*c[q+3];
          }
        }
      }
    }
  }
  float lm[8];
  #pragma unroll
  for (int o = 0; o < 8; ++o){
    float v = act ? fminf(fminf(fabsf(a[o][0]),fabsf(a[o][1])),
                          fminf(fabsf(a[o][2]),fabsf(a[o][3]))) : 3.4e38f;
    #pragma unroll
    for (int off = 32; off > 0; off >>= 1) v = fminf(v, __shfl_xor(v, off));
    lm[o] = v;
    if (act){
      *(float4*)(out + ((size_t)(bl*8+o))*HW + (Y0+ty)*H + X0 + 4*tx) =
          make_float4(a[o][0],a[o][1],a[o][2],a[o][3]);
    }
  }
  if ((threadIdx.x & 63) == 0){
    #pragma unroll
    for (int o = 0; o < 8; ++o) atomicMin(mn + bl*8 + o, __float_as_uint(lm[o]));
  }
}

// 4x4 stride-2 transposed conv of (-x) (pad 1). Block = 32x32 OUTPUT tile, all 8 o.
__global__ void __launch_bounds__(BLK) convt_t8(
    const float* __restrict__ x, const float* __restrict__ wall,
    const float* __restrict__ ball, float* __restrict__ out,
    unsigned* __restrict__ mn, int H, int b0, int s, int tpr){
  __shared__ float tile[8*18*20];
  const int tiles = tpr*tpr;
  const int bl = blockIdx.x / tiles;
  const int t  = blockIdx.x - bl*tiles;
  const int Y0 = (t/tpr)*32, X0 = (t - (t/tpr)*tpr)*32;  // output coords
  const int bg = b0 + bl;
  const float* wb = wall + (size_t)(s*64+bg)*1024;
  const float* bb = ball + (s*64+bg)*8;
  const int Ho = 2*H, HWo = Ho*Ho, HW = H*H;
  const float* xb = x + (size_t)bl*8*HW;
  const int ry0 = Y0/2 - 1, rx0 = X0/2 - 1;
  {
    float vb[12];
    #pragma unroll
    for (int k = 0; k < 12; ++k){
      int e = threadIdx.x + k*BLK;
      float v = 0.f;
      if (e < 2880){
        int cc = e % 20; int rr = (e/20) % 18; int ch = e/(20*18);
        int gy = ry0 + rr, gx = rx0 + cc;
        if (cc < 18 && (unsigned)gy < (unsigned)H && (unsigned)gx < (unsigned)H)
          v = xb[(size_t)ch*HW + gy*H + gx];
      }
      vb[k] = v;
    }
    #pragma unroll
    for (int k = 0; k < 12; ++k){
      int e = threadIdx.x + k*BLK;
      if (e < 2880) tile[e] = vb[k];
    }
  }
  __syncthreads();
  const int tx = threadIdx.x & 7;
  const int ty2 = threadIdx.x >> 3;
  const int row = (ty2 < 16) ? 2*ty2 : 2*(ty2-16)+1;   // wave-parity-uniform
  const int yodd = __builtin_amdgcn_readfirstlane(row & 1);
  const int half = row >> 1;
  const int pA = yodd ? 0 : 1, rA = yodd ? half+2 : half+1;
  const int pB = yodd ? 2 : 3, rB = yodd ? half+1 : half;
  float a[8][4];
  #pragma unroll
  for (int o = 0; o < 8; ++o){
    float b = bb[o];
    a[o][0]=b; a[o][1]=b; a[o][2]=b; a[o][3]=b;
  }
  #pragma unroll 1
  for (int i = 0; i < 8; ++i){
    #pragma unroll
    for (int rt = 0; rt < 2; ++rt){
      const int p = rt ? pB : pA;
      const int ri = rt ? rB : rA;
      const float* rowp = tile + i*360 + ri*20 + 2*tx;
      float e0 = rowp[0], e1 = rowp[1], e2 = rowp[2], e3 = rowp[3];
      const float* wip = wb + (i*4+p)*32;   // [q][o], uniform
      float w[32];
      #pragma unroll
      for (int k = 0; k < 32; ++k) w[k] = wip[k];
      #pragma unroll
      for (int o = 0; o < 8; ++o){
        float w1 = w[8+o];  a[o][0] -= w1*e1; a[o][2] -= w1*e2;  // x even, q=1
        float w3 = w[24+o]; a[o][0] -= w3*e0; a[o][2] -= w3*e1;  // x even, q=3
        float w0 = w[o];    a[o][1] -= w0*e2; a[o][3] -= w0*e3;  // x odd,  q=0
        float w2 = w[16+o]; a[o][1] -= w2*e1; a[o][3] -= w2*e2;  // x odd,  q=2
      }
    }
  }
  float lm[8];
  #pragma unroll
  for (int o = 0; o < 8; ++o){
    float v = fminf(fminf(fabsf(a[o][0]),fabsf(a[o][1])),
                    fminf(fabsf(a[o][2]),fabsf(a[o][3])));
    #pragma unroll
    for (int off = 32; off > 0; off >>= 1) v = fminf(v, __shfl_xor(v, off));
    lm[o] = v;
    *(float4*)(out + ((size_t)(bl*8+o))*HWo + (Y0+row)*Ho + X0 + 4*tx) =
        make_float4(a[o][0],a[o][1],a[o][2],a[o][3]);
  }
  if ((threadIdx.x & 63) == 0){
    #pragma unroll
    for (int o = 0; o < 8; ++o) atomicMin(mn + bl*8 + o, __float_as_uint(lm[o]));
  }
}

// POLYPHASE 5x5-on-upsampled conv. Quarter-res log halo in LDS (clamp-extended),
// 4x4 quarter-taps per fine-parity; exact zero-pad fallback on image-edge px
// (fallback j-loop FULLY UNROLLED so accumulator indexing stays static).
__global__ void __launch_bounds__(BLK) convm_poly(
    const float* __restrict__ X, const float* __restrict__ wqall,
    const float* __restrict__ wall, const float* __restrict__ ball,
    float* __restrict__ out, unsigned* __restrict__ mn,
    int Hi, int b0, int s, int tpr){
  __shared__ __align__(16) float lbuf[8*20*24];     // 15.4 KB, stride 24
  const int tiles = tpr*tpr;
  const int bl = blockIdx.x / tiles;
  const int t  = blockIdx.x - bl*tiles;
  const int Y0 = (t/tpr)*32, X0 = (t - (t/tpr)*tpr)*32;
  const int bg = b0 + bl;
  const float* wq = wqall + (size_t)(s*64+bg)*4096;
  const float* w5 = wall + (size_t)(s*64+bg)*1600;  // original [i][p][q][o]
  const float* bb = ball + (s*64+bg)*8;
  const int Hq = Hi >> 1, HWq = Hq*Hq;
  const int HW = Hi*Hi;
  const float* xb = X + (size_t)bl*8*HWq;
  const int LY0 = (Y0 >> 1) - 2;
  const int LX0 = (X0 >> 1) - 2;
  // stage: 8 ch x 20 x 20 (stride 24), clamp-extended, log applied
  for (int e = threadIdx.x; e < 3200; e += BLK){
    int cc = e % 20; int rr = (e/20) % 20; int ch = e/400;
    int ly = LY0 + rr; ly = (ly < 0) ? 0 : ((ly >= Hq) ? Hq-1 : ly);
    int lx = LX0 + cc; lx = (lx < 0) ? 0 : ((lx >= Hq) ? Hq-1 : lx);
    lbuf[ch*480 + rr*24 + cc] = __logf(fabsf(xb[(size_t)ch*HWq + ly*Hq + lx]) + 1.0f);
  }
  __syncthreads();
  const int tx = threadIdx.x & 7;
  const int ty2 = threadIdx.x >> 3;
  const int row = (ty2 < 16) ? 2*ty2 : 2*(ty2-16)+1;   // wave-parity-uniform
  const int ey = __builtin_amdgcn_readfirstlane(row & 1);
  const int y = Y0 + row;
  const int rbase = (row >> 1) + ey;                   // rel row of ky=0 tap
  float a[8][4];
  #pragma unroll
  for (int o = 0; o < 8; ++o){
    float b = bb[o];
    a[o][0]=b; a[o][1]=b; a[o][2]=b; a[o][3]=b;
  }
  #pragma unroll 1
  for (int i = 0; i < 8; ++i){
    const float* lch = lbuf + i*480;
    #pragma unroll
    for (int ky = 0; ky < 4; ++ky){
      const float* lr = lch + (rbase + ky)*24 + 2*tx;
      float2 f0 = *(const float2*)lr;
      float2 f1 = *(const float2*)(lr+2);
      float2 f2 = *(const float2*)(lr+4);
      float l[6] = {f0.x,f0.y,f1.x,f1.y,f2.x,f2.y};
      const float* wk = wq + (((i*2+ey)*4 + ky) << 6);  // [ex][kx][o], uniform
      float w[64];
      #pragma unroll
      for (int k = 0; k < 64; ++k) w[k] = wk[k];
      #pragma unroll
      for (int kx = 0; kx < 4; ++kx){
        #pragma unroll
        for (int o = 0; o < 8; ++o){
          float w0 = w[kx*8+o];        // ex=0
          float w1 = w[32+kx*8+o];     // ex=1
          a[o][0] += w0*l[kx];   a[o][2] += w0*l[kx+1];
          a[o][1] += w1*l[kx+1]; a[o][3] += w1*l[kx+2];
        }
      }
    }
  }
  // exact fallback for fine px whose 5x5 taps exit the image (zero-padded there).
  // j fully unrolled -> a[o][j] static indexing (keeps accumulators in VGPRs).
  if (Y0 == 0 || Y0 == Hi-32 || X0 == 0 || X0 == Hi-32){
    const bool ybad = (y < 2) || (y >= Hi-2);
    #pragma unroll
    for (int j = 0; j < 4; ++j){
      int x = X0 + 4*tx + j;
      if (ybad || x < 2 || x >= Hi-2){
        float acc2[8];
        #pragma unroll
        for (int o = 0; o < 8; ++o) acc2[o] = bb[o];
        #pragma unroll 1
        for (int i = 0; i < 8; ++i){
          const float* lch = lbuf + i*480;
          #pragma unroll 1
          for (int p = 0; p < 5; ++p){
            int tf = y + p - 2;
            if ((unsigned)tf >= (unsigned)Hi) continue;
            int jt = tf >> 1;
            int nt = (tf & 1) ? jt+1 : jt-1;
            nt = (nt < 0) ? 0 : ((nt >= Hq) ? Hq-1 : nt);
            int rj = jt - LY0, rn = nt - LY0;
            #pragma unroll 1
            for (int q = 0; q < 5; ++q){
              int uf = x + q - 2;
              if ((unsigned)uf >= (unsigned)Hi) continue;
              int ju = uf >> 1;
              int nu = (uf & 1) ? ju+1 : ju-1;
              nu = (nu < 0) ? 0 : ((nu >= Hq) ? Hq-1 : nu);
              int cj = ju - LX0, cn = nu - LX0;
              float U = 0.5625f*lch[rj*24+cj] + 0.1875f*(lch[rj*24+cn] + lch[rn*24+cj])
                      + 0.0625f*lch[rn*24+cn];
              const float* wv = w5 + ((i*5+p)*5+q)*8;
              #pragma unroll
              for (int o = 0; o < 8; ++o) acc2[o] += wv[o]*U;
            }
          }
        }
        #pragma unroll
        for (int o = 0; o < 8; ++o) a[o][j] = acc2[o];
      }
    }
  }
  float lm[8];
  #pragma unroll
  for (int o = 0; o < 8; ++o){
    float v = fminf(fminf(fabsf(a[o][0]),fabsf(a[o][1])),
                    fminf(fabsf(a[o][2]),fabsf(a[o][3])));
    #pragma unroll
    for (int off = 32; off > 0; off >>= 1) v = fminf(v, __shfl_xor(v, off));
    lm[o] = v;
    *(float4*)(out + ((size_t)(bl*8+o))*HW + (Y0+row)*Hi + X0 + 4*tx) =
        make_float4(a[o][0],a[o][1],a[o][2],a[o][3]);
  }
  if ((threadIdx.x & 63) == 0){
    #pragma unroll
    for (int o = 0; o < 8; ++o) atomicMin(mn + bl*8 + o, __float_as_uint(lm[o]));
  }
}

// s<3: next_x = (dln(Dr)[nearest-up] + dln(Dt)) * dln(Dm), into X. Quarter-px threads.
__global__ void combine_kernel(const float* __restrict__ dr, const float* __restrict__ dt,
                               const float* __restrict__ dm,
                               const unsigned* __restrict__ mn, int maps,
                               float* __restrict__ outx, int H, int total){
  int Ho = 2*H, HWo = Ho*Ho, HW = H*H;
  for (int e = blockIdx.x*blockDim.x + threadIdx.x; e < total; e += gridDim.x*blockDim.x){
    int m = e / HW;
    int qpx = e - m*HW;
    int qy = qpx / H, qx = qpx - qy*H;
    float mr = __uint_as_float(mn[m]);
    float mt = __uint_as_float(mn[maps + m]);
    float mm = __uint_as_float(mn[2*maps + m]);
    float r = dln_one(dr[(size_t)m*HW + qpx], mr);
    #pragma unroll
    for (int dy = 0; dy < 2; ++dy){
      size_t base = (size_t)m*HWo + (2*qy+dy)*Ho + 2*qx;
      float2 tv = *(const float2*)(dt + base);
      float2 mv = *(const float2*)(dm + base);
      float2 ov;
      ov.x = (r + dln_one(tv.x, mt)) * dln_one(mv.x, mm);
      ov.y = (r + dln_one(tv.y, mt)) * dln_one(mv.y, mm);
      *(float2*)(outx + base) = ov;
    }
  }
}

// s==3: combine + final dynamic 1x1 conv (8->3 ch) fused, writes d_out.
__global__ void combineF_kernel(const float* __restrict__ dr, const float* __restrict__ dt,
                                const float* __restrict__ dm,
                                const unsigned* __restrict__ mn, int maps,
                                const float* __restrict__ wo, const float* __restrict__ bo,
                                float* __restrict__ out, int b0, int total){
  for (int e = blockIdx.x*blockDim.x + threadIdx.x; e < total; e += gridDim.x*blockDim.x){
    int bl = e >> 14;
    int qpx = e & 16383;
    int qy = qpx >> 7, qx = qpx & 127;
    int bg = b0 + bl;
    float r[8], mtv[8], mmv[8];
    #pragma unroll
    for (int o = 0; o < 8; ++o){
      int m = bl*8 + o;
      float mr = __uint_as_float(mn[m]);
      mtv[o] = __uint_as_float(mn[maps + m]);
      mmv[o] = __uint_as_float(mn[2*maps + m]);
      r[o] = dln_one(dr[(size_t)m*16384 + qpx], mr);
    }
    #pragma unroll
    for (int dy = 0; dy < 2; ++dy){
      int y = 2*qy + dy, xx = 2*qx;
      float2 acc[3];
      #pragma unroll
      for (int of = 0; of < 3; ++of){
        float b = bo[bg*3 + of];
        acc[of].x = b; acc[of].y = b;
      }
      #pragma unroll
      for (int o = 0; o < 8; ++o){
        size_t base = (size_t)(bl*8+o)*65536 + y*256 + xx;
        float2 tv = *(const float2*)(dt + base);
        float2 mv = *(const float2*)(dm + base);
        float vx = (r[o] + dln_one(tv.x, mtv[o])) * dln_one(mv.x, mmv[o]);
        float vy = (r[o] + dln_one(tv.y, mtv[o])) * dln_one(mv.y, mmv[o]);
        #pragma unroll
        for (int of = 0; of < 3; ++of){
          float w = wo[bg*24 + of*8 + o];
          acc[of].x += w*vx; acc[of].y += w*vy;
        }
      }
      #pragma unroll
      for (int of = 0; of < 3; ++of){
        *(float2*)(out + ((size_t)(bg*3 + of))*65536 + y*256 + xx) = acc[of];
      }
    }
  }
}

static inline int grid_for(long long total){
  long long g = (total + BLK - 1) / BLK;
  if (g > 16384) g = 16384;
  if (g < 1) g = 1;
  return (int)g;
}

extern "C" void kernel_launch(void* const* d_in, const int* in_sizes, int n_in,
                              void* d_out, int out_size, void* d_ws, size_t ws_size,
                              hipStream_t stream){
  (void)in_sizes; (void)n_in; (void)out_size;
  const int*   ids   = (const int*)d_in[0];
  const float* cache = (const float*)d_in[1];
  const float* lat   = (const float*)d_in[2];
  const float* Wr = (const float*)d_in[3];
  const float* Ur = (const float*)d_in[4];
  const float* Vr = (const float*)d_in[5];
  const float* Br = (const float*)d_in[6];
  const float* Wt = (const float*)d_in[7];
  const float* Ut = (const float*)d_in[8];
  const float* Vt = (const float*)d_in[9];
  const float* Bt = (const float*)d_in[10];
  const float* Wm = (const float*)d_in[11];
  const float* Um = (const float*)d_in[12];
  const float* Vm = (const float*)d_in[13];
  const float* Bm = (const float*)d_in[14];
  const float* Wo = (const float*)d_in[15];
  const float* Uo = (const float*)d_in[16];
  const float* Vo = (const float*)d_in[17];
  const float* Bo = (const float*)d_in[18];
  float* out = (float*)d_out;
  float* ws  = (float*)d_ws;

  size_t off = 0;
  auto alloc = [&](size_t n){ size_t o = off; off += n; return o; };
  size_t o_ctx = alloc(2048);
  size_t o_ur = alloc(4*64*128),  o_vr = alloc(4*64*1152);
  size_t o_ut = alloc(4*64*128),  o_vt = alloc(4*64*2048);
  size_t o_um = alloc(4*64*128),  o_vm = alloc(4*64*3200);
  size_t o_br = alloc(4*64*8), o_bt = alloc(4*64*8), o_bm = alloc(4*64*8);
  size_t o_uo = alloc(64*48), o_vo = alloc(64*128), o_bo = alloc(64*3);
  size_t o_wr = alloc(4*64*8*72), o_wt = alloc(4*64*8*128), o_wm = alloc(4*64*8*200);
  size_t o_wo = alloc(64*24);
  size_t o_wmq = alloc(4*64*4096);       // polyphase convm weights
  size_t o_mn = alloc(4*3*512);          // [stage][3][maps]
  size_t small_end = off;

  // per sample: X (8*128^2) + D (8*128^2) + T (8*256^2) + M (8*256^2)
  const size_t perS = 2*(size_t)131072 + 2*(size_t)524288;
  size_t ws_f = ws_size / sizeof(float);
  int nb = 64;
  while (nb > 1 && small_end + (size_t)nb*perS > ws_f) nb >>= 1;

  size_t o_X = small_end;
  size_t o_D = o_X + (size_t)nb*131072;
  size_t o_T = o_D + (size_t)nb*131072;
  size_t o_M = o_T + (size_t)nb*524288;
  unsigned* mn = (unsigned*)(ws + o_mn);

  gather_ctx_kernel<<<8, BLK, 0, stream>>>(ids, cache, ws + o_ctx);

  W1Args a1;
  a1.M[0]=Ur;  a1.out[0]=ws+o_ur;
  a1.M[1]=Vr;  a1.out[1]=ws+o_vr;
  a1.M[2]=Ut;  a1.out[2]=ws+o_ut;
  a1.M[3]=Vt;  a1.out[3]=ws+o_vt;
  a1.M[4]=Um;  a1.out[4]=ws+o_um;
  a1.M[5]=Vm;  a1.out[5]=ws+o_vm;
  a1.M[6]=Br;  a1.out[6]=ws+o_br;
  a1.M[7]=Bt;  a1.out[7]=ws+o_bt;
  a1.M[8]=Bm;  a1.out[8]=ws+o_bm;
  a1.M[9]=Uo;  a1.out[9]=ws+o_uo;
  a1.M[10]=Vo; a1.out[10]=ws+o_vo;
  a1.M[11]=Bo; a1.out[11]=ws+o_bo;
  w1_kernel<<<256, BLK, 0, stream>>>(ws + o_ctx, a1);

  W2Args a2;
  a2.W[0]=Wr; a2.u[0]=ws+o_ur; a2.v[0]=ws+o_vr; a2.out[0]=ws+o_wr;
  a2.W[1]=Wt; a2.u[1]=ws+o_ut; a2.v[1]=ws+o_vt; a2.out[1]=ws+o_wt;
  a2.W[2]=Wm; a2.u[2]=ws+o_um; a2.v[2]=ws+o_vm; a2.out[2]=ws+o_wm;
  a2.W[3]=Wo; a2.u[3]=ws+o_uo; a2.v[3]=ws+o_vo; a2.out[3]=ws+o_wo;
  w2_kernel<<<256, BLK, 0, stream>>>(a2);
  w2m_kernel<<<512, BLK, 0, stream>>>(ws+o_wm, ws+o_wmq);

  for (int b0 = 0; b0 < 64; b0 += nb){
    gather_x_kernel<<<grid_for((long long)nb*2048), BLK, 0, stream>>>(
        ids, lat, ws+o_X, b0, nb);
    int maps = nb*8;
    init_min_kernel<<<(4*3*maps + BLK-1)/BLK, BLK, 0, stream>>>(mn, 4*3*maps);
    int H = 16;
    for (int s = 0; s < 4; ++s){
      int Ho = 2*H;
      int tprR = (H >= 32) ? H/32 : 1;
      int tprO = Ho/32;
      unsigned* mns = mn + (size_t)s*3*maps;
      convr_t8<<<nb*tprR*tprR, BLK, 0, stream>>>(ws+o_X, ws+o_wr, ws+o_br, ws+o_D, mns,            H,  b0, s, tprR);
      convt_t8<<<nb*tprO*tprO, BLK, 0, stream>>>(ws+o_X, ws+o_wt, ws+o_bt, ws+o_T, mns + maps,     H,  b0, s, tprO);
      convm_poly<<<nb*tprO*tprO, BLK, 0, stream>>>(ws+o_X, ws+o_wmq, ws+o_wm, ws+o_bm, ws+o_M,
                                                   mns + 2*maps, Ho, b0, s, tprO);
      if (s < 3){
        long long totalq = (long long)maps*H*H;
        combine_kernel<<<grid_for(totalq), BLK, 0, stream>>>(
            ws+o_D, ws+o_T, ws+o_M, mns, maps, ws+o_X, H, (int)totalq);
      } else {
        long long totalf = (long long)nb*16384;
        combineF_kernel<<<grid_for(totalf), BLK, 0, stream>>>(
            ws+o_D, ws+o_T, ws+o_M, mns, maps, ws+o_wo, ws+o_bo, out, b0, (int)totalf);
      }
      H = Ho;
    }
  }
}

// Round 12
// 1267.128 us; speedup vs baseline: 2.2540x; 2.1607x over previous
//
#include <hip/hip_runtime.h>
#include <math.h>

// ExperimentalModel_1752346656819: 4-stage dynamic-conv decoder, fp32 end-to-end.
// R11: polyphase convm REVERTED to R7 tile-expand (measured faster). The three
// independent per-stage convs (convr/convt/convm) are horizontally FUSED into
// one dispatch (block type by blockIdx range, 31KB LDS union) so their
// latency-bound blocks co-schedule and per-stage dispatch count drops 3->1.

#define BLK 256
#define EF 2.7182818284590452f

struct W1Args { const float* M[12]; float* out[12]; };
struct W2Args { const float* W[4]; const float* u[4]; const float* v[4]; float* out[4]; };

__device__ __forceinline__ float dln_one(float y, float m){
  float a = fabsf(y) - m;
  float v = __logf(__logf(a + EF) + 0.01f);
  return (y > 0.0f) ? v : -v;
}

__global__ void gather_ctx_kernel(const int* __restrict__ ids,
                                  const float* __restrict__ cache,
                                  float* __restrict__ ctx){
  int e = blockIdx.x*blockDim.x + threadIdx.x;
  if (e < 64*32){
    int b = e >> 5, l = e & 31;
    ctx[e] = cache[(size_t)ids[b]*32 + l];
  }
}

__global__ void gather_x_kernel(const int* __restrict__ ids,
                                const float* __restrict__ lat,
                                float* __restrict__ X, int b0, int nb){
  int total = nb*2048;
  int e = blockIdx.x*blockDim.x + threadIdx.x;
  if (e < total){
    int bl = e >> 11;
    int r  = e & 2047;
    X[e] = lat[(size_t)ids[b0+bl]*2048 + r];
  }
}

__global__ void w1_kernel(const float* __restrict__ ctx, W1Args args){
  const int S[12] = {4,4,4,4,4,4,4,4,4,1,1,1};
  const int K[12] = {128,1152,128,2048,128,3200,8,8,8,48,128,3};
  int tid = blockIdx.x*blockDim.x + threadIdx.x;
  int nth = gridDim.x*blockDim.x;
  for (int seg = 0; seg < 12; ++seg){
    const float* M = args.M[seg];
    float* out = args.out[seg];
    int Ks = K[seg];
    int total = S[seg]*64*Ks;
    for (int e = tid; e < total; e += nth){
      int k = e % Ks;
      int b = (e / Ks) % 64;
      int s = e / (Ks*64);
      const float* Ms = M + (size_t)s*32*Ks + k;
      const float* cb = ctx + b*32;
      float acc = 0.f;
      #pragma unroll
      for (int l = 0; l < 32; ++l) acc += cb[l]*Ms[(size_t)l*Ks];
      out[e] = acc;
    }
  }
}

// Dynamic weights. Segs 0-2 TRANSPOSED to [s][b][i][p][q][o]; seg 3 [b][o][i].
__global__ void w2_kernel(W2Args args){
  const int S[4] = {4,4,4,1};
  const int O[4] = {8,8,8,3};
  const int K[4] = {72,128,200,8};
  const int KH[4] = {3,4,5,1};
  int tid = blockIdx.x*blockDim.x + threadIdx.x;
  int nth = gridDim.x*blockDim.x;
  for (int seg = 0; seg < 4; ++seg){
    int Os = O[seg], Ks = K[seg];
    int kh = KH[seg], kk = kh*kh;
    int total = S[seg]*64*Os*Ks;
    const float* Wt = args.W[seg];
    const float* u = args.u[seg];
    const float* v = args.v[seg];
    float* out = args.out[seg];
    for (int e = tid; e < total; e += nth){
      int k = e % Ks;
      int o = (e/Ks) % Os;
      int b = (e/(Ks*Os)) % 64;
      int s = e/(Ks*Os*64);
      const float* us = u + (size_t)(s*64+b)*16*Os;
      const float* vs = v + (size_t)(s*64+b)*16*Ks;
      float mod = 0.f;
      #pragma unroll
      for (int r = 0; r < 16; ++r) mod += us[r*Os+o]*vs[r*Ks+k];
      float val = Wt[(size_t)(s*Os+o)*Ks + k] * (1.0f + mod + 1e-3f);
      size_t dst;
      if (seg < 3){
        int i = k / kk, r2 = k - i*kk, p = r2 / kh, q = r2 - p*kh;
        dst = (size_t)(s*64+b)*(8*Ks) + (size_t)(((i*kh+p)*kh+q)*8 + o);
      } else {
        dst = (size_t)b*24 + o*8 + k;
      }
      out[dst] = val;
    }
  }
}

__global__ void init_min_kernel(unsigned* __restrict__ mn, int n){
  int e = blockIdx.x*blockDim.x + threadIdx.x;
  if (e < n) mn[e] = 0x7F800000u;   // +inf
}

// Fused per-stage conv kernel: blocks [0,gR) = 3x3 conv; [gR,gR+gT) = 4x4
// stride-2 transposed conv; [gR+gT, ...) = 5x5 conv on bilinear-up(log).
// LDS union: 7760 floats (convm: 5760 tile + 2000 lbuf).
__global__ void __launch_bounds__(BLK) conv3_fused(
    const float* __restrict__ X,
    const float* __restrict__ wr, const float* __restrict__ br,
    const float* __restrict__ wt, const float* __restrict__ bt,
    const float* __restrict__ wm, const float* __restrict__ bm,
    float* __restrict__ D, float* __restrict__ T, float* __restrict__ M,
    unsigned* __restrict__ mn, int maps, int H, int b0, int s,
    int tprR, int tprO, int gR, int gT){
  __shared__ __align__(16) float smem[7760];
  const int bid = blockIdx.x;

  if (bid < gR){
    // ---------------- 3x3 conv (pad 1), two phases of 4 input ch ----------------
    float* tile = smem;                       // 4*34*36 = 4896
    const int tiles = tprR*tprR;
    const int bl = bid / tiles;
    const int t  = bid - bl*tiles;
    const int Y0 = (t/tprR)*32, X0 = (t - (t/tprR)*tprR)*32;
    const int bg = b0 + bl;
    const float* wb = wr + (size_t)(s*64+bg)*576;
    const float* bb = br + (s*64+bg)*8;
    const int HW = H*H;
    const float* xb = X + (size_t)bl*8*HW;
    const int tx = threadIdx.x & 7, ty = threadIdx.x >> 3;
    const bool act = (Y0+ty < H) && (X0+4*tx < H);  // only false when H==16
    float a[8][4];
    #pragma unroll
    for (int o = 0; o < 8; ++o){
      float b = bb[o];
      a[o][0]=b; a[o][1]=b; a[o][2]=b; a[o][3]=b;
    }
    #pragma unroll 1
    for (int ph = 0; ph < 2; ++ph){
      __syncthreads();
      {
        float vb[10];
        #pragma unroll
        for (int k = 0; k < 10; ++k){
          int e = threadIdx.x + k*BLK;
          int cc = e % 36; int rr = (e/36) % 34; int c4 = e/(36*34);
          int gy = Y0 - 1 + rr, gx = X0 - 1 + cc;
          float v = 0.f;
          if (cc < 34 && (unsigned)gy < (unsigned)H && (unsigned)gx < (unsigned)H)
            v = xb[(size_t)(ph*4 + c4)*HW + gy*H + gx];
          vb[k] = v;
        }
        #pragma unroll
        for (int k = 0; k < 10; ++k) tile[threadIdx.x + k*BLK] = vb[k];
      }
      {
        float vb[10];
        #pragma unroll
        for (int k = 0; k < 10; ++k){
          int e = threadIdx.x + (k+10)*BLK;
          float v = 0.f;
          if (e < 4896){
            int cc = e % 36; int rr = (e/36) % 34; int c4 = e/(36*34);
            int gy = Y0 - 1 + rr, gx = X0 - 1 + cc;
            if (cc < 34 && (unsigned)gy < (unsigned)H && (unsigned)gx < (unsigned)H)
              v = xb[(size_t)(ph*4 + c4)*HW + gy*H + gx];
          }
          vb[k] = v;
        }
        #pragma unroll
        for (int k = 0; k < 10; ++k){
          int e = threadIdx.x + (k+10)*BLK;
          if (e < 4896) tile[e] = vb[k];
        }
      }
      __syncthreads();
      #pragma unroll 1
      for (int i = 0; i < 4; ++i){
        const float* tch = tile + i*1224;
        const int ig = ph*4 + i;
        #pragma unroll
        for (int p = 0; p < 3; ++p){
          const float* row = tch + (ty+p)*36 + 4*tx;
          float4 c0 = *(const float4*)row;
          float4 c1 = *(const float4*)(row+4);
          float c[8] = {c0.x,c0.y,c0.z,c0.w,c1.x,c1.y,c1.z,c1.w};
          const float* wip = wb + (ig*3+p)*24;
          float w[24];
          #pragma unroll
          for (int k = 0; k < 24; ++k) w[k] = wip[k];
          #pragma unroll
          for (int q = 0; q < 3; ++q){
            #pragma unroll
            for (int o = 0; o < 8; ++o){
              float wq = w[q*8+o];
              a[o][0] += wq*c[q];   a[o][1] += wq*c[q+1];
              a[o][2] += wq*c[q+2]; a[o][3] += wq*c[q+3];
            }
          }
        }
      }
    }
    float lm[8];
    #pragma unroll
    for (int o = 0; o < 8; ++o){
      float v = act ? fminf(fminf(fabsf(a[o][0]),fabsf(a[o][1])),
                            fminf(fabsf(a[o][2]),fabsf(a[o][3]))) : 3.4e38f;
      #pragma unroll
      for (int off = 32; off > 0; off >>= 1) v = fminf(v, __shfl_xor(v, off));
      lm[o] = v;
      if (act){
        *(float4*)(D + ((size_t)(bl*8+o))*HW + (Y0+ty)*H + X0 + 4*tx) =
            make_float4(a[o][0],a[o][1],a[o][2],a[o][3]);
      }
    }
    if ((threadIdx.x & 63) == 0){
      #pragma unroll
      for (int o = 0; o < 8; ++o) atomicMin(mn + bl*8 + o, __float_as_uint(lm[o]));
    }
    return;
  }

  if (bid < gR + gT){
    // ------- 4x4 stride-2 transposed conv of (-x) (pad 1), 32x32 out tile -------
    float* tile = smem;                       // 8*18*20 = 2880
    const int idx = bid - gR;
    const int tiles = tprO*tprO;
    const int bl = idx / tiles;
    const int t  = idx - bl*tiles;
    const int Y0 = (t/tprO)*32, X0 = (t - (t/tprO)*tprO)*32;  // output coords
    const int bg = b0 + bl;
    const float* wb = wt + (size_t)(s*64+bg)*1024;
    const float* bb = bt + (s*64+bg)*8;
    const int Ho = 2*H, HWo = Ho*Ho, HW = H*H;
    const float* xb = X + (size_t)bl*8*HW;
    const int ry0 = Y0/2 - 1, rx0 = X0/2 - 1;
    {
      float vb[12];
      #pragma unroll
      for (int k = 0; k < 12; ++k){
        int e = threadIdx.x + k*BLK;
        float v = 0.f;
        if (e < 2880){
          int cc = e % 20; int rr = (e/20) % 18; int ch = e/(20*18);
          int gy = ry0 + rr, gx = rx0 + cc;
          if (cc < 18 && (unsigned)gy < (unsigned)H && (unsigned)gx < (unsigned)H)
            v = xb[(size_t)ch*HW + gy*H + gx];
        }
        vb[k] = v;
      }
      #pragma unroll
      for (int k = 0; k < 12; ++k){
        int e = threadIdx.x + k*BLK;
        if (e < 2880) tile[e] = vb[k];
      }
    }
    __syncthreads();
    const int tx = threadIdx.x & 7;
    const int ty2 = threadIdx.x >> 3;
    const int row = (ty2 < 16) ? 2*ty2 : 2*(ty2-16)+1;   // wave-parity-uniform
    const int yodd = __builtin_amdgcn_readfirstlane(row & 1);
    const int half = row >> 1;
    const int pA = yodd ? 0 : 1, rA = yodd ? half+2 : half+1;
    const int pB = yodd ? 2 : 3, rB = yodd ? half+1 : half;
    float a[8][4];
    #pragma unroll
    for (int o = 0; o < 8; ++o){
      float b = bb[o];
      a[o][0]=b; a[o][1]=b; a[o][2]=b; a[o][3]=b;
    }
    #pragma unroll 1
    for (int i = 0; i < 8; ++i){
      #pragma unroll
      for (int rt = 0; rt < 2; ++rt){
        const int p = rt ? pB : pA;
        const int ri = rt ? rB : rA;
        const float* rowp = tile + i*360 + ri*20 + 2*tx;
        float e0 = rowp[0], e1 = rowp[1], e2 = rowp[2], e3 = rowp[3];
        const float* wip = wb + (i*4+p)*32;   // [q][o], uniform
        float w[32];
        #pragma unroll
        for (int k = 0; k < 32; ++k) w[k] = wip[k];
        #pragma unroll
        for (int o = 0; o < 8; ++o){
          float w1 = w[8+o];  a[o][0] -= w1*e1; a[o][2] -= w1*e2;  // x even, q=1
          float w3 = w[24+o]; a[o][0] -= w3*e0; a[o][2] -= w3*e1;  // x even, q=3
          float w0 = w[o];    a[o][1] -= w0*e2; a[o][3] -= w0*e3;  // x odd,  q=0
          float w2 = w[16+o]; a[o][1] -= w2*e1; a[o][3] -= w2*e2;  // x odd,  q=2
        }
      }
    }
    float lm[8];
    #pragma unroll
    for (int o = 0; o < 8; ++o){
      float v = fminf(fminf(fabsf(a[o][0]),fabsf(a[o][1])),
                      fminf(fabsf(a[o][2]),fabsf(a[o][3])));
      #pragma unroll
      for (int off = 32; off > 0; off >>= 1) v = fminf(v, __shfl_xor(v, off));
      lm[o] = v;
      *(float4*)(T + ((size_t)(bl*8+o))*HWo + (Y0+row)*Ho + X0 + 4*tx) =
          make_float4(a[o][0],a[o][1],a[o][2],a[o][3]);
    }
    if ((threadIdx.x & 63) == 0){
      #pragma unroll
      for (int o = 0; o < 8; ++o)
        atomicMin(mn + maps + bl*8 + o, __float_as_uint(lm[o]));
    }
    return;
  }

  // --- 5x5 conv (pad 2) on bilinear-up(log(|X|+1)); X quarter-res; 2 phases ---
  {
    float* tile = smem;                       // 4*36*40 = 5760
    float* lbuf = smem + 5760;                // 4*20*25 = 2000
    const int idx = bid - gR - gT;
    const int tiles = tprO*tprO;
    const int bl = idx / tiles;
    const int t  = idx - bl*tiles;
    const int Y0 = (t/tprO)*32, X0 = (t - (t/tprO)*tprO)*32;
    const int bg = b0 + bl;
    const float* wb = wm + (size_t)(s*64+bg)*1600;
    const float* bb = bm + (s*64+bg)*8;
    const int Hi = 2*H;
    const int Hq = H, HWq = Hq*Hq;
    const int HW = Hi*Hi;
    const float* xb = X + (size_t)bl*8*HWq;
    const int LY0 = ((Y0-2)>>1) - 1;
    const int LX0 = ((X0-2)>>1) - 1;
    const int tx = threadIdx.x & 7, ty = threadIdx.x >> 3;
    float a[8][4];
    #pragma unroll
    for (int o = 0; o < 8; ++o){
      float b = bb[o];
      a[o][0]=b; a[o][1]=b; a[o][2]=b; a[o][3]=b;
    }
    #pragma unroll 1
    for (int ph = 0; ph < 2; ++ph){
      __syncthreads();
      // stage quarter-res log halo: 4 ch x 20 x 25(stride, 22 used) = 2000
      #pragma unroll
      for (int k = 0; k < 8; ++k){
        int e = threadIdx.x + k*BLK;
        if (e < 2000){
          int c4 = e/500; int r2 = e - c4*500; int rr = r2/25; int cc = r2 - rr*25;
          int ly = LY0 + rr, lx = LX0 + cc;
          float v = 0.f;
          if (cc < 22 && (unsigned)ly < (unsigned)Hq && (unsigned)lx < (unsigned)Hq){
            float xv = xb[(size_t)(ph*4 + c4)*HWq + ly*Hq + lx];
            v = __logf(fabsf(xv) + 1.0f);
          }
          lbuf[e] = v;
        }
      }
      __syncthreads();
      // expand 2x bilinear (half-pixel, edge clamp) into 36x40 halo tile
      #pragma unroll 1
      for (int e = threadIdx.x; e < 5760; e += BLK){
        int c4 = e/1440; int r2 = e - c4*1440; int rr = r2/40; int cc = r2 - rr*40;
        int gy = Y0 - 2 + rr, gx = X0 - 2 + cc;
        float f = 0.f;
        if (cc < 36 && (unsigned)gy < (unsigned)Hi && (unsigned)gx < (unsigned)Hi){
          int jy = gy >> 1;
          int ny = (gy & 1) ? ((jy+1 < Hq) ? jy+1 : Hq-1) : ((jy > 0) ? jy-1 : 0);
          int jx = gx >> 1;
          int nx = (gx & 1) ? ((jx+1 < Hq) ? jx+1 : Hq-1) : ((jx > 0) ? jx-1 : 0);
          const float* lb = lbuf + c4*500;
          float f00 = lb[(jy-LY0)*25 + (jx-LX0)];
          float f01 = lb[(jy-LY0)*25 + (nx-LX0)];
          float f10 = lb[(ny-LY0)*25 + (jx-LX0)];
          float f11 = lb[(ny-LY0)*25 + (nx-LX0)];
          f = 0.5625f*f00 + 0.1875f*(f01 + f10) + 0.0625f*f11;
        }
        tile[e] = f;
      }
      __syncthreads();
      #pragma unroll 1
      for (int i = 0; i < 4; ++i){
        const float* tch = tile + i*1440;
        const int ig = ph*4 + i;
        #pragma unroll
        for (int p = 0; p < 5; ++p){
          const float* row = tch + (ty+p)*40 + 4*tx;
          float4 c0 = *(const float4*)row;
          float4 c1 = *(const float4*)(row+4);
          float c[8] = {c0.x,c0.y,c0.z,c0.w,c1.x,c1.y,c1.z,c1.w};
          const float* wip = wb + (ig*5+p)*40;   // [q][o], uniform
          float w[40];
          #pragma unroll
          for (int k = 0; k < 40; ++k) w[k] = wip[k];
          #pragma unroll
          for (int q = 0; q < 5; ++q){
            #pragma unroll
            for (int o = 0; o < 8; ++o){
              float wq = w[q*8+o];
              a[o][0] += wq*c[q];   a[o][1] += wq*c[q+1];
              a[o][2] += wq*c[q+2]; a[o][3] += wq*c[q+3];
            }
          }
        }
      }
    }
    float lm[8];
    #pragma unroll
    for (int o = 0; o < 8; ++o){
      float v = fminf(fminf(fabsf(a[o][0]),fabsf(a[o][1])),
                      fminf(fabsf(a[o][2]),fabsf(a[o][3])));
      #pragma unroll
      for (int off = 32; off > 0; off >>= 1) v = fminf(v, __shfl_xor(v, off));
      lm[o] = v;
      *(float4*)(M + ((size_t)(bl*8+o))*HW + (Y0+ty)*Hi + X0 + 4*tx) =
          make_float4(a[o][0],a[o][1],a[o][2],a[o][3]);
    }
    if ((threadIdx.x & 63) == 0){
      #pragma unroll
      for (int o = 0; o < 8; ++o)
        atomicMin(mn + 2*maps + bl*8 + o, __float_as_uint(lm[o]));
    }
  }
}

// s<3: next_x = (dln(Dr)[nearest-up] + dln(Dt)) * dln(Dm), into X. Quarter-px threads.
__global__ void combine_kernel(const float* __restrict__ dr, const float* __restrict__ dt,
                               const float* __restrict__ dm,
                               const unsigned* __restrict__ mn, int maps,
                               float* __restrict__ outx, int H, int total){
  int Ho = 2*H, HWo = Ho*Ho, HW = H*H;
  for (int e = blockIdx.x*blockDim.x + threadIdx.x; e < total; e += gridDim.x*blockDim.x){
    int m = e / HW;
    int qpx = e - m*HW;
    int qy = qpx / H, qx = qpx - qy*H;
    float mr = __uint_as_float(mn[m]);
    float mt = __uint_as_float(mn[maps + m]);
    float mm = __uint_as_float(mn[2*maps + m]);
    float r = dln_one(dr[(size_t)m*HW + qpx], mr);
    #pragma unroll
    for (int dy = 0; dy < 2; ++dy){
      size_t base = (size_t)m*HWo + (2*qy+dy)*Ho + 2*qx;
      float2 tv = *(const float2*)(dt + base);
      float2 mv = *(const float2*)(dm + base);
      float2 ov;
      ov.x = (r + dln_one(tv.x, mt)) * dln_one(mv.x, mm);
      ov.y = (r + dln_one(tv.y, mt)) * dln_one(mv.y, mm);
      *(float2*)(outx + base) = ov;
    }
  }
}

// s==3: combine + final dynamic 1x1 conv (8->3 ch) fused, writes d_out.
__global__ void combineF_kernel(const float* __restrict__ dr, const float* __restrict__ dt,
                                const float* __restrict__ dm,
                                const unsigned* __restrict__ mn, int maps,
                                const float* __restrict__ wo, const float* __restrict__ bo,
                                float* __restrict__ out, int b0, int total){
  for (int e = blockIdx.x*blockDim.x + threadIdx.x; e < total; e += gridDim.x*blockDim.x){
    int bl = e >> 14;
    int qpx = e & 16383;
    int qy = qpx >> 7, qx = qpx & 127;
    int bg = b0 + bl;
    float r[8], mtv[8], mmv[8];
    #pragma unroll
    for (int o = 0; o < 8; ++o){
      int m = bl*8 + o;
      float mr = __uint_as_float(mn[m]);
      mtv[o] = __uint_as_float(mn[maps + m]);
      mmv[o] = __uint_as_float(mn[2*maps + m]);
      r[o] = dln_one(dr[(size_t)m*16384 + qpx], mr);
    }
    #pragma unroll
    for (int dy = 0; dy < 2; ++dy){
      int y = 2*qy + dy, xx = 2*qx;
      float2 acc[3];
      #pragma unroll
      for (int of = 0; of < 3; ++of){
        float b = bo[bg*3 + of];
        acc[of].x = b; acc[of].y = b;
      }
      #pragma unroll
      for (int o = 0; o < 8; ++o){
        size_t base = (size_t)(bl*8+o)*65536 + y*256 + xx;
        float2 tv = *(const float2*)(dt + base);
        float2 mv = *(const float2*)(dm + base);
        float vx = (r[o] + dln_one(tv.x, mtv[o])) * dln_one(mv.x, mmv[o]);
        float vy = (r[o] + dln_one(tv.y, mtv[o])) * dln_one(mv.y, mmv[o]);
        #pragma unroll
        for (int of = 0; of < 3; ++of){
          float w = wo[bg*24 + of*8 + o];
          acc[of].x += w*vx; acc[of].y += w*vy;
        }
      }
      #pragma unroll
      for (int of = 0; of < 3; ++of){
        *(float2*)(out + ((size_t)(bg*3 + of))*65536 + y*256 + xx) = acc[of];
      }
    }
  }
}

static inline int grid_for(long long total){
  long long g = (total + BLK - 1) / BLK;
  if (g > 16384) g = 16384;
  if (g < 1) g = 1;
  return (int)g;
}

extern "C" void kernel_launch(void* const* d_in, const int* in_sizes, int n_in,
                              void* d_out, int out_size, void* d_ws, size_t ws_size,
                              hipStream_t stream){
  (void)in_sizes; (void)n_in; (void)out_size;
  const int*   ids   = (const int*)d_in[0];
  const float* cache = (const float*)d_in[1];
  const float* lat   = (const float*)d_in[2];
  const float* Wr = (const float*)d_in[3];
  const float* Ur = (const float*)d_in[4];
  const float* Vr = (const float*)d_in[5];
  const float* Br = (const float*)d_in[6];
  const float* Wt = (const float*)d_in[7];
  const float* Ut = (const float*)d_in[8];
  const float* Vt = (const float*)d_in[9];
  const float* Bt = (const float*)d_in[10];
  const float* Wm = (const float*)d_in[11];
  const float* Um = (const float*)d_in[12];
  const float* Vm = (const float*)d_in[13];
  const float* Bm = (const float*)d_in[14];
  const float* Wo = (const float*)d_in[15];
  const float* Uo = (const float*)d_in[16];
  const float* Vo = (const float*)d_in[17];
  const float* Bo = (const float*)d_in[18];
  float* out = (float*)d_out;
  float* ws  = (float*)d_ws;

  size_t off = 0;
  auto alloc = [&](size_t n){ size_t o = off; off += n; return o; };
  size_t o_ctx = alloc(2048);
  size_t o_ur = alloc(4*64*128),  o_vr = alloc(4*64*1152);
  size_t o_ut = alloc(4*64*128),  o_vt = alloc(4*64*2048);
  size_t o_um = alloc(4*64*128),  o_vm = alloc(4*64*3200);
  size_t o_br = alloc(4*64*8), o_bt = alloc(4*64*8), o_bm = alloc(4*64*8);
  size_t o_uo = alloc(64*48), o_vo = alloc(64*128), o_bo = alloc(64*3);
  size_t o_wr = alloc(4*64*8*72), o_wt = alloc(4*64*8*128), o_wm = alloc(4*64*8*200);
  size_t o_wo = alloc(64*24);
  size_t o_mn = alloc(4*3*512);          // [stage][3][maps]
  size_t small_end = off;

  // per sample: X (8*128^2) + D (8*128^2) + T (8*256^2) + M (8*256^2)
  const size_t perS = 2*(size_t)131072 + 2*(size_t)524288;
  size_t ws_f = ws_size / sizeof(float);
  int nb = 64;
  while (nb > 1 && small_end + (size_t)nb*perS > ws_f) nb >>= 1;

  size_t o_X = small_end;
  size_t o_D = o_X + (size_t)nb*131072;
  size_t o_T = o_D + (size_t)nb*131072;
  size_t o_M = o_T + (size_t)nb*524288;
  unsigned* mn = (unsigned*)(ws + o_mn);

  gather_ctx_kernel<<<8, BLK, 0, stream>>>(ids, cache, ws + o_ctx);

  W1Args a1;
  a1.M[0]=Ur;  a1.out[0]=ws+o_ur;
  a1.M[1]=Vr;  a1.out[1]=ws+o_vr;
  a1.M[2]=Ut;  a1.out[2]=ws+o_ut;
  a1.M[3]=Vt;  a1.out[3]=ws+o_vt;
  a1.M[4]=Um;  a1.out[4]=ws+o_um;
  a1.M[5]=Vm;  a1.out[5]=ws+o_vm;
  a1.M[6]=Br;  a1.out[6]=ws+o_br;
  a1.M[7]=Bt;  a1.out[7]=ws+o_bt;
  a1.M[8]=Bm;  a1.out[8]=ws+o_bm;
  a1.M[9]=Uo;  a1.out[9]=ws+o_uo;
  a1.M[10]=Vo; a1.out[10]=ws+o_vo;
  a1.M[11]=Bo; a1.out[11]=ws+o_bo;
  w1_kernel<<<256, BLK, 0, stream>>>(ws + o_ctx, a1);

  W2Args a2;
  a2.W[0]=Wr; a2.u[0]=ws+o_ur; a2.v[0]=ws+o_vr; a2.out[0]=ws+o_wr;
  a2.W[1]=Wt; a2.u[1]=ws+o_ut; a2.v[1]=ws+o_vt; a2.out[1]=ws+o_wt;
  a2.W[2]=Wm; a2.u[2]=ws+o_um; a2.v[2]=ws+o_vm; a2.out[2]=ws+o_wm;
  a2.W[3]=Wo; a2.u[3]=ws+o_uo; a2.v[3]=ws+o_vo; a2.out[3]=ws+o_wo;
  w2_kernel<<<256, BLK, 0, stream>>>(a2);

  for (int b0 = 0; b0 < 64; b0 += nb){
    gather_x_kernel<<<grid_for((long long)nb*2048), BLK, 0, stream>>>(
        ids, lat, ws+o_X, b0, nb);
    int maps = nb*8;
    init_min_kernel<<<(4*3*maps + BLK-1)/BLK, BLK, 0, stream>>>(mn, 4*3*maps);
    int H = 16;
    for (int s = 0; s < 4; ++s){
      int Ho = 2*H;
      int tprR = (H >= 32) ? H/32 : 1;
      int tprO = Ho/32;
      int gR = nb*tprR*tprR;
      int gT = nb*tprO*tprO;
      int gM = nb*tprO*tprO;
      unsigned* mns = mn + (size_t)s*3*maps;
      conv3_fused<<<gR+gT+gM, BLK, 0, stream>>>(
          ws+o_X, ws+o_wr, ws+o_br, ws+o_wt, ws+o_bt, ws+o_wm, ws+o_bm,
          ws+o_D, ws+o_T, ws+o_M, mns, maps, H, b0, s, tprR, tprO, gR, gT);
      if (s < 3){
        long long totalq = (long long)maps*H*H;
        combine_kernel<<<grid_for(totalq), BLK, 0, stream>>>(
            ws+o_D, ws+o_T, ws+o_M, mns, maps, ws+o_X, H, (int)totalq);
      } else {
        long long totalf = (long long)nb*16384;
        combineF_kernel<<<grid_for(totalf), BLK, 0, stream>>>(
            ws+o_D, ws+o_T, ws+o_M, mns, maps, ws+o_wo, ws+o_bo, out, b0, (int)totalf);
      }
      H = Ho;
    }
  }
}